// Round 1
// baseline (594.947 us; speedup 1.0000x reference)
//
#include <hip/hip_runtime.h>

// GNN: 2 x (SimpleConv(mean, cat) -> Linear(256->128) -> ReLU)
// N=50000 nodes, E=640000 edges, H=128. All fp32.
//
// Pipeline (all on `stream`, graph-capture safe):
//   k_detect : probe whether edge index buffer is int32 or int64 (stride flag)
//   k_zero   : zero degree + cursor
//   k_count  : degree histogram (int atomics)
//   k_scan   : single-block exclusive scan -> CSR offsets
//   k_fill   : bucket edge ids into CSR
//   k_agg    : per-node gather/mean + concat  -> cat [N,256]
//   k_gemm   : tiled fp32 GEMM [N,256]@[256,128] + bias + relu
//   (agg+gemm repeated for layer 2, writing d_out)

#define HDIM 128
#define BM 64
#define BK 32
#define BN 128

__global__ void k_detect(const int* __restrict__ edge, int nwords, int* __restrict__ flag) {
    // If edge is int64 (little-endian, values < 2^31), every odd 32-bit word is 0.
    __shared__ int s_or;
    if (threadIdx.x == 0) s_or = 0;
    __syncthreads();
    int i = threadIdx.x * 2 + 1;
    int v = (i < nwords) ? edge[i] : 0;
    if (v != 0) atomicOr(&s_or, 1);
    __syncthreads();
    if (threadIdx.x == 0) flag[0] = (s_or == 0) ? 1 : 0;  // shift: 1 => int64, 0 => int32
}

__global__ void k_zero(int* __restrict__ p, int n) {
    int i = blockIdx.x * blockDim.x + threadIdx.x;
    if (i < n) p[i] = 0;
}

__global__ void k_count(const int* __restrict__ edge, int E, const int* __restrict__ flag,
                        int* __restrict__ deg) {
    int sh = flag[0];
    int i = blockIdx.x * blockDim.x + threadIdx.x;
    if (i < E) {
        int d = edge[(size_t)(E + i) << sh];
        atomicAdd(&deg[d], 1);
    }
}

__global__ __launch_bounds__(1024) void k_scan(const int* __restrict__ deg,
                                               int* __restrict__ off, int N) {
    __shared__ int sm[1024];
    int tid = threadIdx.x;
    int chunk = (N + 1023) >> 10;
    int i0 = tid * chunk;
    int sum = 0;
    for (int c = 0; c < chunk; ++c) {
        int i = i0 + c;
        if (i < N) sum += deg[i];
    }
    sm[tid] = sum;
    __syncthreads();
    for (int s = 1; s < 1024; s <<= 1) {
        int t = (tid >= s) ? sm[tid - s] : 0;
        __syncthreads();
        sm[tid] += t;
        __syncthreads();
    }
    int run = sm[tid] - sum;  // exclusive prefix
    for (int c = 0; c < chunk; ++c) {
        int i = i0 + c;
        if (i < N) {
            off[i] = run;
            run += deg[i];
        }
    }
    if (tid == 1023) off[N] = run;
}

__global__ void k_fill(const int* __restrict__ edge, int E, const int* __restrict__ flag,
                       const int* __restrict__ off, int* __restrict__ cursor,
                       int* __restrict__ eid) {
    int sh = flag[0];
    int i = blockIdx.x * blockDim.x + threadIdx.x;
    if (i < E) {
        int d = edge[(size_t)(E + i) << sh];
        int pos = off[d] + atomicAdd(&cursor[d], 1);
        eid[pos] = i;
    }
}

// One block (128 threads) per node: agg = mean_{e: dst=n}( x[src[e]] * att[e] );
// cat[n] = [ x[n], agg ]
__global__ __launch_bounds__(128) void k_agg(const float* __restrict__ x,
                                             const int* __restrict__ edge,
                                             const int* __restrict__ flag,
                                             const float* __restrict__ att,
                                             const int* __restrict__ off,
                                             const int* __restrict__ eid,
                                             float* __restrict__ cat, int N, int E) {
    int n = blockIdx.x;
    int h = threadIdx.x;  // 0..127
    int sh = flag[0];
    int o0 = off[n], o1 = off[n + 1];
    float sum = 0.f;
    for (int j = o0; j < o1; ++j) {
        int e = eid[j];
        int s = edge[(size_t)e << sh];
        float a = att[e];
        sum += x[(size_t)s * HDIM + h] * a;
    }
    float m = fmaxf((float)(o1 - o0), 1.0f);
    cat[(size_t)n * 256 + h] = x[(size_t)n * HDIM + h];
    cat[(size_t)n * 256 + 128 + h] = sum / m;
}

// out[M,128] = relu( A[M,256] @ W[256,128] + b ), fp32, tile 64x128, 256 threads.
__global__ __launch_bounds__(256) void k_gemm_relu(const float* __restrict__ A,
                                                   const float* __restrict__ Wm,
                                                   const float* __restrict__ bias,
                                                   float* __restrict__ out, int M) {
    __shared__ __align__(16) float AsT[BK][BM + 4];   // A tile, transposed (k-major)
    __shared__ __align__(16) float Bs[BK][BN + 4];

    int tid = threadIdx.x;
    int tx = tid & 31;    // 32 col-groups of 4
    int ty = tid >> 5;    // 8 row-groups of 8
    int rowBase = blockIdx.x * BM;

    float acc[8][4];
#pragma unroll
    for (int i = 0; i < 8; ++i)
#pragma unroll
        for (int j = 0; j < 4; ++j) acc[i][j] = 0.f;

    for (int k0 = 0; k0 < 256; k0 += BK) {
        // Stage A tile (BM x BK) transposed into LDS
#pragma unroll
        for (int l = 0; l < 2; ++l) {
            int id = tid + 256 * l;      // 0..511 float4s
            int r = id >> 3;             // 0..63
            int kq = id & 7;             // 0..7 (x4 floats)
            int g = rowBase + r;
            float4 v = make_float4(0.f, 0.f, 0.f, 0.f);
            if (g < M) v = *(const float4*)&A[(size_t)g * 256 + k0 + kq * 4];
            AsT[kq * 4 + 0][r] = v.x;
            AsT[kq * 4 + 1][r] = v.y;
            AsT[kq * 4 + 2][r] = v.z;
            AsT[kq * 4 + 3][r] = v.w;
        }
        // Stage B tile (BK x BN)
#pragma unroll
        for (int l = 0; l < 4; ++l) {
            int id = tid + 256 * l;      // 0..1023 float4s
            int kr = id >> 5;            // 0..31
            int cq = id & 31;            // 0..31 (x4 floats)
            float4 v = *(const float4*)&Wm[(size_t)(k0 + kr) * 128 + cq * 4];
            *(float4*)&Bs[kr][cq * 4] = v;
        }
        __syncthreads();

#pragma unroll
        for (int kk = 0; kk < BK; ++kk) {
            float4 a0 = *(const float4*)&AsT[kk][ty * 8];
            float4 a1 = *(const float4*)&AsT[kk][ty * 8 + 4];
            float4 b = *(const float4*)&Bs[kk][tx * 4];
            float av[8] = {a0.x, a0.y, a0.z, a0.w, a1.x, a1.y, a1.z, a1.w};
            float bv[4] = {b.x, b.y, b.z, b.w};
#pragma unroll
            for (int i = 0; i < 8; ++i)
#pragma unroll
                for (int j = 0; j < 4; ++j) acc[i][j] = fmaf(av[i], bv[j], acc[i][j]);
        }
        __syncthreads();
    }

    float bv[4];
#pragma unroll
    for (int j = 0; j < 4; ++j) bv[j] = bias[tx * 4 + j];
#pragma unroll
    for (int i = 0; i < 8; ++i) {
        int g = rowBase + ty * 8 + i;
        if (g < M) {
            float4 o;
            o.x = fmaxf(acc[i][0] + bv[0], 0.f);
            o.y = fmaxf(acc[i][1] + bv[1], 0.f);
            o.z = fmaxf(acc[i][2] + bv[2], 0.f);
            o.w = fmaxf(acc[i][3] + bv[3], 0.f);
            *(float4*)&out[(size_t)g * 128 + tx * 4] = o;
        }
    }
}

extern "C" void kernel_launch(void* const* d_in, const int* in_sizes, int n_in,
                              void* d_out, int out_size, void* d_ws, size_t ws_size,
                              hipStream_t stream) {
    const float* data = (const float*)d_in[0];
    const int* edge = (const int*)d_in[1];
    const float* att = (const float*)d_in[2];
    const float* w1 = (const float*)d_in[3];
    const float* b1 = (const float*)d_in[4];
    const float* w2 = (const float*)d_in[5];
    const float* b2 = (const float*)d_in[6];

    const int N = in_sizes[0] / HDIM;
    const int E = in_sizes[1] / 2;

    char* ws = (char*)d_ws;
    size_t o = 0;
    auto carve = [&](size_t bytes) -> char* {
        char* r = ws + o;
        o = (o + bytes + 255) & ~(size_t)255;
        return r;
    };
    int* flag = (int*)carve(16);
    int* deg = (int*)carve((size_t)2 * N * 4);  // deg[N] + cursor[N], contiguous
    int* cursor = deg + N;
    int* off = (int*)carve((size_t)(N + 1) * 4);
    int* eid = (int*)carve((size_t)E * 4);
    float* cat = (float*)carve((size_t)N * 256 * 4);
    float* out1 = (float*)carve((size_t)N * 128 * 4);
    float* outF = (float*)d_out;

    int nw = 2 * E < 512 ? 2 * E : 512;
    k_detect<<<1, 256, 0, stream>>>(edge, nw, flag);
    k_zero<<<(2 * N + 255) / 256, 256, 0, stream>>>(deg, 2 * N);
    k_count<<<(E + 255) / 256, 256, 0, stream>>>(edge, E, flag, deg);
    k_scan<<<1, 1024, 0, stream>>>(deg, off, N);
    k_fill<<<(E + 255) / 256, 256, 0, stream>>>(edge, E, flag, off, cursor, eid);

    int gb = (N + BM - 1) / BM;
    // Layer 1
    k_agg<<<N, 128, 0, stream>>>(data, edge, flag, att, off, eid, cat, N, E);
    k_gemm_relu<<<gb, 256, 0, stream>>>(cat, w1, b1, out1, N);
    // Layer 2
    k_agg<<<N, 128, 0, stream>>>(out1, edge, flag, att, off, eid, cat, N, E);
    k_gemm_relu<<<gb, 256, 0, stream>>>(cat, w2, b2, outF, N);
}

// Round 2
// 454.327 us; speedup vs baseline: 1.3095x; 1.3095x over previous
//
#include <hip/hip_runtime.h>

// GNN: 2 x (SimpleConv(mean, cat) -> Linear(256->128) -> ReLU)
// N=50000 nodes, E=640000 edges, H=128. All fp32.
//
// R1: k_agg was latency-bound (133us, VALUBusy 5.6%, 2.2TB/s): serial chain
//     eid->edge->att->x per edge. R2: pack (src,att) in CSR order at fill
//     time, stage pairs in LDS, unroll gather x4 for MLP.

#define HDIM 128
#define BM 64
#define BK 32
#define BN 128

__global__ void k_detect(const int* __restrict__ edge, int nwords, int* __restrict__ flag) {
    // If edge is int64 (little-endian, values < 2^31), every odd 32-bit word is 0.
    __shared__ int s_or;
    if (threadIdx.x == 0) s_or = 0;
    __syncthreads();
    int i = threadIdx.x * 2 + 1;
    int v = (i < nwords) ? edge[i] : 0;
    if (v != 0) atomicOr(&s_or, 1);
    __syncthreads();
    if (threadIdx.x == 0) flag[0] = (s_or == 0) ? 1 : 0;  // shift: 1 => int64, 0 => int32
}

__global__ void k_zero(int* __restrict__ p, int n) {
    int i = blockIdx.x * blockDim.x + threadIdx.x;
    if (i < n) p[i] = 0;
}

__global__ void k_count(const int* __restrict__ edge, int E, const int* __restrict__ flag,
                        int* __restrict__ deg) {
    int sh = flag[0];
    int i = blockIdx.x * blockDim.x + threadIdx.x;
    if (i < E) {
        int d = edge[(size_t)(E + i) << sh];
        atomicAdd(&deg[d], 1);
    }
}

__global__ __launch_bounds__(1024) void k_scan(const int* __restrict__ deg,
                                               int* __restrict__ off, int N) {
    __shared__ int sm[1024];
    int tid = threadIdx.x;
    int chunk = (N + 1023) >> 10;
    int i0 = tid * chunk;
    int sum = 0;
    for (int c = 0; c < chunk; ++c) {
        int i = i0 + c;
        if (i < N) sum += deg[i];
    }
    sm[tid] = sum;
    __syncthreads();
    for (int s = 1; s < 1024; s <<= 1) {
        int t = (tid >= s) ? sm[tid - s] : 0;
        __syncthreads();
        sm[tid] += t;
        __syncthreads();
    }
    int run = sm[tid] - sum;  // exclusive prefix
    for (int c = 0; c < chunk; ++c) {
        int i = i0 + c;
        if (i < N) {
            off[i] = run;
            run += deg[i];
        }
    }
    if (tid == 1023) off[N] = run;
}

// Bucket edges into CSR slots, writing packed {src, att} pairs directly.
__global__ void k_fill(const int* __restrict__ edge, int E, const int* __restrict__ flag,
                       const float* __restrict__ att,
                       const int* __restrict__ off, int* __restrict__ cursor,
                       float2* __restrict__ pse) {
    int sh = flag[0];
    int i = blockIdx.x * blockDim.x + threadIdx.x;
    if (i < E) {
        int s = edge[(size_t)i << sh];        // src
        int d = edge[(size_t)(E + i) << sh];  // dst
        int pos = off[d] + atomicAdd(&cursor[d], 1);
        pse[pos] = make_float2(__int_as_float(s), att[i]);
    }
}

// One block (128 threads = 2 waves) per node.
// agg = mean_{e: dst=n}( x[src[e]] * att[e] );  cat[n] = [ x[n], agg ]
__global__ __launch_bounds__(128) void k_agg(const float* __restrict__ x,
                                             const float2* __restrict__ pse,
                                             const int* __restrict__ off,
                                             float* __restrict__ cat, int N) {
    int n = blockIdx.x;
    int h = threadIdx.x;  // 0..127
    __shared__ float2 sp[128];
    int o0 = off[n], o1 = off[n + 1];
    int deg = o1 - o0;
    float sum = 0.f;
    for (int base = 0; base < deg; base += 128) {
        int cnt = min(128, deg - base);
        __syncthreads();
        if (h < cnt) sp[h] = pse[o0 + base + h];
        __syncthreads();
        int j = 0;
        for (; j + 4 <= cnt; j += 4) {
            float2 p0 = sp[j + 0];
            float2 p1 = sp[j + 1];
            float2 p2 = sp[j + 2];
            float2 p3 = sp[j + 3];
            float v0 = x[(size_t)__float_as_int(p0.x) * HDIM + h];
            float v1 = x[(size_t)__float_as_int(p1.x) * HDIM + h];
            float v2 = x[(size_t)__float_as_int(p2.x) * HDIM + h];
            float v3 = x[(size_t)__float_as_int(p3.x) * HDIM + h];
            sum = fmaf(v0, p0.y, sum);
            sum = fmaf(v1, p1.y, sum);
            sum = fmaf(v2, p2.y, sum);
            sum = fmaf(v3, p3.y, sum);
        }
        for (; j < cnt; ++j) {
            float2 p = sp[j];
            sum = fmaf(x[(size_t)__float_as_int(p.x) * HDIM + h], p.y, sum);
        }
    }
    float m = fmaxf((float)deg, 1.0f);
    cat[(size_t)n * 256 + h] = x[(size_t)n * HDIM + h];
    cat[(size_t)n * 256 + 128 + h] = sum / m;
}

// out[M,128] = relu( A[M,256] @ W[256,128] + b ), fp32, tile 64x128, 256 threads.
__global__ __launch_bounds__(256) void k_gemm_relu(const float* __restrict__ A,
                                                   const float* __restrict__ Wm,
                                                   const float* __restrict__ bias,
                                                   float* __restrict__ out, int M) {
    __shared__ __align__(16) float AsT[BK][BM + 4];   // A tile, transposed (k-major)
    __shared__ __align__(16) float Bs[BK][BN + 4];

    int tid = threadIdx.x;
    int tx = tid & 31;    // 32 col-groups of 4
    int ty = tid >> 5;    // 8 row-groups of 8
    int rowBase = blockIdx.x * BM;

    float acc[8][4];
#pragma unroll
    for (int i = 0; i < 8; ++i)
#pragma unroll
        for (int j = 0; j < 4; ++j) acc[i][j] = 0.f;

    for (int k0 = 0; k0 < 256; k0 += BK) {
        // Stage A tile (BM x BK) transposed into LDS
#pragma unroll
        for (int l = 0; l < 2; ++l) {
            int id = tid + 256 * l;      // 0..511 float4s
            int r = id >> 3;             // 0..63
            int kq = id & 7;             // 0..7 (x4 floats)
            int g = rowBase + r;
            float4 v = make_float4(0.f, 0.f, 0.f, 0.f);
            if (g < M) v = *(const float4*)&A[(size_t)g * 256 + k0 + kq * 4];
            AsT[kq * 4 + 0][r] = v.x;
            AsT[kq * 4 + 1][r] = v.y;
            AsT[kq * 4 + 2][r] = v.z;
            AsT[kq * 4 + 3][r] = v.w;
        }
        // Stage B tile (BK x BN)
#pragma unroll
        for (int l = 0; l < 4; ++l) {
            int id = tid + 256 * l;      // 0..1023 float4s
            int kr = id >> 5;            // 0..31
            int cq = id & 31;            // 0..31 (x4 floats)
            float4 v = *(const float4*)&Wm[(size_t)(k0 + kr) * 128 + cq * 4];
            *(float4*)&Bs[kr][cq * 4] = v;
        }
        __syncthreads();

#pragma unroll
        for (int kk = 0; kk < BK; ++kk) {
            float4 a0 = *(const float4*)&AsT[kk][ty * 8];
            float4 a1 = *(const float4*)&AsT[kk][ty * 8 + 4];
            float4 b = *(const float4*)&Bs[kk][tx * 4];
            float av[8] = {a0.x, a0.y, a0.z, a0.w, a1.x, a1.y, a1.z, a1.w};
            float bv[4] = {b.x, b.y, b.z, b.w};
#pragma unroll
            for (int i = 0; i < 8; ++i)
#pragma unroll
                for (int j = 0; j < 4; ++j) acc[i][j] = fmaf(av[i], bv[j], acc[i][j]);
        }
        __syncthreads();
    }

    float bv[4];
#pragma unroll
    for (int j = 0; j < 4; ++j) bv[j] = bias[tx * 4 + j];
#pragma unroll
    for (int i = 0; i < 8; ++i) {
        int g = rowBase + ty * 8 + i;
        if (g < M) {
            float4 o;
            o.x = fmaxf(acc[i][0] + bv[0], 0.f);
            o.y = fmaxf(acc[i][1] + bv[1], 0.f);
            o.z = fmaxf(acc[i][2] + bv[2], 0.f);
            o.w = fmaxf(acc[i][3] + bv[3], 0.f);
            *(float4*)&out[(size_t)g * 128 + tx * 4] = o;
        }
    }
}

extern "C" void kernel_launch(void* const* d_in, const int* in_sizes, int n_in,
                              void* d_out, int out_size, void* d_ws, size_t ws_size,
                              hipStream_t stream) {
    const float* data = (const float*)d_in[0];
    const int* edge = (const int*)d_in[1];
    const float* att = (const float*)d_in[2];
    const float* w1 = (const float*)d_in[3];
    const float* b1 = (const float*)d_in[4];
    const float* w2 = (const float*)d_in[5];
    const float* b2 = (const float*)d_in[6];

    const int N = in_sizes[0] / HDIM;
    const int E = in_sizes[1] / 2;

    char* ws = (char*)d_ws;
    size_t o = 0;
    auto carve = [&](size_t bytes) -> char* {
        char* r = ws + o;
        o = (o + bytes + 255) & ~(size_t)255;
        return r;
    };
    int* flag = (int*)carve(16);
    int* deg = (int*)carve((size_t)2 * N * 4);  // deg[N] + cursor[N], contiguous
    int* cursor = deg + N;
    int* off = (int*)carve((size_t)(N + 1) * 4);
    float2* pse = (float2*)carve((size_t)E * 8);  // packed {src, att} in CSR order
    float* cat = (float*)carve((size_t)N * 256 * 4);
    float* out1 = (float*)carve((size_t)N * 128 * 4);
    float* outF = (float*)d_out;

    int nw = 2 * E < 512 ? 2 * E : 512;
    k_detect<<<1, 256, 0, stream>>>(edge, nw, flag);
    k_zero<<<(2 * N + 255) / 256, 256, 0, stream>>>(deg, 2 * N);
    k_count<<<(E + 255) / 256, 256, 0, stream>>>(edge, E, flag, deg);
    k_scan<<<1, 1024, 0, stream>>>(deg, off, N);
    k_fill<<<(E + 255) / 256, 256, 0, stream>>>(edge, E, flag, att, off, cursor, pse);

    int gb = (N + BM - 1) / BM;
    // Layer 1
    k_agg<<<N, 128, 0, stream>>>(data, pse, off, cat, N);
    k_gemm_relu<<<gb, 256, 0, stream>>>(cat, w1, b1, out1, N);
    // Layer 2
    k_agg<<<N, 128, 0, stream>>>(out1, pse, off, cat, N);
    k_gemm_relu<<<gb, 256, 0, stream>>>(cat, w2, b2, outF, N);
}

// Round 3
// 366.140 us; speedup vs baseline: 1.6249x; 1.2409x over previous
//
#include <hip/hip_runtime.h>

// GNN: 2 x (SimpleConv(mean, cat) -> Linear(256->128) -> ReLU)
// N=50000 nodes, E=640000 edges, H=128. All fp32.
//
// R1: k_agg latency-bound -> packed (src,att) CSR + LDS stage + x4 unroll.
// R2: k_scan (single-block, 90us!) -> 3-phase multi-block scan (~10us).

#define HDIM 128
#define BM 64
#define BK 32
#define BN 128
#define SCAN_CHUNK 2048   // elements per block in the scan (256 thr x 8)

__global__ void k_detect(const int* __restrict__ edge, int nwords, int* __restrict__ flag) {
    // If edge is int64 (little-endian, values < 2^31), every odd 32-bit word is 0.
    __shared__ int s_or;
    if (threadIdx.x == 0) s_or = 0;
    __syncthreads();
    int i = threadIdx.x * 2 + 1;
    int v = (i < nwords) ? edge[i] : 0;
    if (v != 0) atomicOr(&s_or, 1);
    __syncthreads();
    if (threadIdx.x == 0) flag[0] = (s_or == 0) ? 1 : 0;  // shift: 1 => int64, 0 => int32
}

__global__ void k_zero(int* __restrict__ p, int n) {
    int i = blockIdx.x * blockDim.x + threadIdx.x;
    if (i < n) p[i] = 0;
}

__global__ void k_count(const int* __restrict__ edge, int E, const int* __restrict__ flag,
                        int* __restrict__ deg) {
    int sh = flag[0];
    int i = blockIdx.x * blockDim.x + threadIdx.x;
    if (i < E) {
        int d = edge[(size_t)(E + i) << sh];
        atomicAdd(&deg[d], 1);
    }
}

// ---- 3-phase scan: deg[N] -> off[N+1] (exclusive) ----
__global__ __launch_bounds__(256) void k_scan1(const int* __restrict__ deg, int N,
                                               int* __restrict__ partial) {
    __shared__ int sm[256];
    int t = threadIdx.x;
    int base = blockIdx.x * SCAN_CHUNK + t * 8;
    int s = 0;
#pragma unroll
    for (int j = 0; j < 8; ++j) {
        int i = base + j;
        if (i < N) s += deg[i];
    }
    sm[t] = s;
    __syncthreads();
    for (int st = 128; st > 0; st >>= 1) {
        if (t < st) sm[t] += sm[t + st];
        __syncthreads();
    }
    if (t == 0) partial[blockIdx.x] = sm[0];
}

__global__ __launch_bounds__(256) void k_scan2(int* __restrict__ partial, int nb) {
    // Exclusive scan of up to 256 block partials, in place.
    __shared__ int sm[256];
    int t = threadIdx.x;
    int v = (t < nb) ? partial[t] : 0;
    sm[t] = v;
    __syncthreads();
    for (int st = 1; st < 256; st <<= 1) {
        int tv = (t >= st) ? sm[t - st] : 0;
        __syncthreads();
        sm[t] += tv;
        __syncthreads();
    }
    if (t < nb) partial[t] = sm[t] - v;  // exclusive
}

__global__ __launch_bounds__(256) void k_scan3(const int* __restrict__ deg, int N,
                                               const int* __restrict__ partial,
                                               int* __restrict__ off) {
    __shared__ int sm[256];
    int t = threadIdx.x;
    int b = blockIdx.x;
    int base = b * SCAN_CHUNK + t * 8;
    int v[8];
    int s = 0;
#pragma unroll
    for (int j = 0; j < 8; ++j) {
        int i = base + j;
        v[j] = (i < N) ? deg[i] : 0;
        s += v[j];
    }
    sm[t] = s;
    __syncthreads();
    for (int st = 1; st < 256; st <<= 1) {
        int tv = (t >= st) ? sm[t - st] : 0;
        __syncthreads();
        sm[t] += tv;
        __syncthreads();
    }
    int run = partial[b] + sm[t] - s;  // exclusive prefix for this thread's range
#pragma unroll
    for (int j = 0; j < 8; ++j) {
        int i = base + j;
        if (i < N) {
            off[i] = run;
            run += v[j];
        }
    }
    if (b == gridDim.x - 1 && t == 255) off[N] = partial[b] + sm[255];
}

// Bucket edges into CSR slots, writing packed {src, att} pairs directly.
__global__ void k_fill(const int* __restrict__ edge, int E, const int* __restrict__ flag,
                       const float* __restrict__ att,
                       const int* __restrict__ off, int* __restrict__ cursor,
                       float2* __restrict__ pse) {
    int sh = flag[0];
    int i = blockIdx.x * blockDim.x + threadIdx.x;
    if (i < E) {
        int s = edge[(size_t)i << sh];        // src
        int d = edge[(size_t)(E + i) << sh];  // dst
        int pos = off[d] + atomicAdd(&cursor[d], 1);
        pse[pos] = make_float2(__int_as_float(s), att[i]);
    }
}

// One block (128 threads = 2 waves) per node.
// agg = mean_{e: dst=n}( x[src[e]] * att[e] );  cat[n] = [ x[n], agg ]
__global__ __launch_bounds__(128) void k_agg(const float* __restrict__ x,
                                             const float2* __restrict__ pse,
                                             const int* __restrict__ off,
                                             float* __restrict__ cat, int N) {
    int n = blockIdx.x;
    int h = threadIdx.x;  // 0..127
    __shared__ float2 sp[128];
    int o0 = off[n], o1 = off[n + 1];
    int deg = o1 - o0;
    float sum = 0.f;
    for (int base = 0; base < deg; base += 128) {
        int cnt = min(128, deg - base);
        __syncthreads();
        if (h < cnt) sp[h] = pse[o0 + base + h];
        __syncthreads();
        int j = 0;
        for (; j + 4 <= cnt; j += 4) {
            float2 p0 = sp[j + 0];
            float2 p1 = sp[j + 1];
            float2 p2 = sp[j + 2];
            float2 p3 = sp[j + 3];
            float v0 = x[(size_t)__float_as_int(p0.x) * HDIM + h];
            float v1 = x[(size_t)__float_as_int(p1.x) * HDIM + h];
            float v2 = x[(size_t)__float_as_int(p2.x) * HDIM + h];
            float v3 = x[(size_t)__float_as_int(p3.x) * HDIM + h];
            sum = fmaf(v0, p0.y, sum);
            sum = fmaf(v1, p1.y, sum);
            sum = fmaf(v2, p2.y, sum);
            sum = fmaf(v3, p3.y, sum);
        }
        for (; j < cnt; ++j) {
            float2 p = sp[j];
            sum = fmaf(x[(size_t)__float_as_int(p.x) * HDIM + h], p.y, sum);
        }
    }
    float m = fmaxf((float)deg, 1.0f);
    cat[(size_t)n * 256 + h] = x[(size_t)n * HDIM + h];
    cat[(size_t)n * 256 + 128 + h] = sum / m;
}

// out[M,128] = relu( A[M,256] @ W[256,128] + b ), fp32, tile 64x128, 256 threads.
__global__ __launch_bounds__(256) void k_gemm_relu(const float* __restrict__ A,
                                                   const float* __restrict__ Wm,
                                                   const float* __restrict__ bias,
                                                   float* __restrict__ out, int M) {
    __shared__ __align__(16) float AsT[BK][BM + 4];   // A tile, transposed (k-major)
    __shared__ __align__(16) float Bs[BK][BN + 4];

    int tid = threadIdx.x;
    int tx = tid & 31;    // 32 col-groups of 4
    int ty = tid >> 5;    // 8 row-groups of 8
    int rowBase = blockIdx.x * BM;

    float acc[8][4];
#pragma unroll
    for (int i = 0; i < 8; ++i)
#pragma unroll
        for (int j = 0; j < 4; ++j) acc[i][j] = 0.f;

    for (int k0 = 0; k0 < 256; k0 += BK) {
        // Stage A tile (BM x BK) transposed into LDS
#pragma unroll
        for (int l = 0; l < 2; ++l) {
            int id = tid + 256 * l;      // 0..511 float4s
            int r = id >> 3;             // 0..63
            int kq = id & 7;             // 0..7 (x4 floats)
            int g = rowBase + r;
            float4 v = make_float4(0.f, 0.f, 0.f, 0.f);
            if (g < M) v = *(const float4*)&A[(size_t)g * 256 + k0 + kq * 4];
            AsT[kq * 4 + 0][r] = v.x;
            AsT[kq * 4 + 1][r] = v.y;
            AsT[kq * 4 + 2][r] = v.z;
            AsT[kq * 4 + 3][r] = v.w;
        }
        // Stage B tile (BK x BN)
#pragma unroll
        for (int l = 0; l < 4; ++l) {
            int id = tid + 256 * l;      // 0..1023 float4s
            int kr = id >> 5;            // 0..31
            int cq = id & 31;            // 0..31 (x4 floats)
            float4 v = *(const float4*)&Wm[(size_t)(k0 + kr) * 128 + cq * 4];
            *(float4*)&Bs[kr][cq * 4] = v;
        }
        __syncthreads();

#pragma unroll
        for (int kk = 0; kk < BK; ++kk) {
            float4 a0 = *(const float4*)&AsT[kk][ty * 8];
            float4 a1 = *(const float4*)&AsT[kk][ty * 8 + 4];
            float4 b = *(const float4*)&Bs[kk][tx * 4];
            float av[8] = {a0.x, a0.y, a0.z, a0.w, a1.x, a1.y, a1.z, a1.w};
            float bv[4] = {b.x, b.y, b.z, b.w};
#pragma unroll
            for (int i = 0; i < 8; ++i)
#pragma unroll
                for (int j = 0; j < 4; ++j) acc[i][j] = fmaf(av[i], bv[j], acc[i][j]);
        }
        __syncthreads();
    }

    float bv[4];
#pragma unroll
    for (int j = 0; j < 4; ++j) bv[j] = bias[tx * 4 + j];
#pragma unroll
    for (int i = 0; i < 8; ++i) {
        int g = rowBase + ty * 8 + i;
        if (g < M) {
            float4 o;
            o.x = fmaxf(acc[i][0] + bv[0], 0.f);
            o.y = fmaxf(acc[i][1] + bv[1], 0.f);
            o.z = fmaxf(acc[i][2] + bv[2], 0.f);
            o.w = fmaxf(acc[i][3] + bv[3], 0.f);
            *(float4*)&out[(size_t)g * 128 + tx * 4] = o;
        }
    }
}

extern "C" void kernel_launch(void* const* d_in, const int* in_sizes, int n_in,
                              void* d_out, int out_size, void* d_ws, size_t ws_size,
                              hipStream_t stream) {
    const float* data = (const float*)d_in[0];
    const int* edge = (const int*)d_in[1];
    const float* att = (const float*)d_in[2];
    const float* w1 = (const float*)d_in[3];
    const float* b1 = (const float*)d_in[4];
    const float* w2 = (const float*)d_in[5];
    const float* b2 = (const float*)d_in[6];

    const int N = in_sizes[0] / HDIM;
    const int E = in_sizes[1] / 2;

    char* ws = (char*)d_ws;
    size_t o = 0;
    auto carve = [&](size_t bytes) -> char* {
        char* r = ws + o;
        o = (o + bytes + 255) & ~(size_t)255;
        return r;
    };
    int* flag = (int*)carve(16);
    int* deg = (int*)carve((size_t)2 * N * 4);  // deg[N] + cursor[N], contiguous
    int* cursor = deg + N;
    int* off = (int*)carve((size_t)(N + 1) * 4);
    int* partial = (int*)carve(256 * 4);
    float2* pse = (float2*)carve((size_t)E * 8);  // packed {src, att} in CSR order
    float* cat = (float*)carve((size_t)N * 256 * 4);
    float* out1 = (float*)carve((size_t)N * 128 * 4);
    float* outF = (float*)d_out;

    int nw = 2 * E < 512 ? 2 * E : 512;
    k_detect<<<1, 256, 0, stream>>>(edge, nw, flag);
    k_zero<<<(2 * N + 255) / 256, 256, 0, stream>>>(deg, 2 * N);
    k_count<<<(E + 255) / 256, 256, 0, stream>>>(edge, E, flag, deg);

    int nb = (N + SCAN_CHUNK - 1) / SCAN_CHUNK;  // 25 for N=50000 (must be <=256)
    k_scan1<<<nb, 256, 0, stream>>>(deg, N, partial);
    k_scan2<<<1, 256, 0, stream>>>(partial, nb);
    k_scan3<<<nb, 256, 0, stream>>>(deg, N, partial, off);

    k_fill<<<(E + 255) / 256, 256, 0, stream>>>(edge, E, flag, att, off, cursor, pse);

    int gb = (N + BM - 1) / BM;
    // Layer 1
    k_agg<<<N, 128, 0, stream>>>(data, pse, off, cat, N);
    k_gemm_relu<<<gb, 256, 0, stream>>>(cat, w1, b1, out1, N);
    // Layer 2
    k_agg<<<N, 128, 0, stream>>>(out1, pse, off, cat, N);
    k_gemm_relu<<<gb, 256, 0, stream>>>(cat, w2, b2, outF, N);
}

// Round 4
// 330.125 us; speedup vs baseline: 1.8022x; 1.1091x over previous
//
#include <hip/hip_runtime.h>

// GNN: 2 x (SimpleConv(mean, cat) -> Linear(256->128) -> ReLU)
// N=50000 nodes, E=640000 edges, H=128.
//
// R1: k_agg latency-bound -> packed (src,att) CSR + LDS stage + x4 unroll.
// R2: k_scan single-block 90us -> 3-phase multi-block scan.
// R3: fp32 VALU GEMM (63us, VALU-bound) + fp32 gather -> bf16 hidden pipeline:
//     bf16 gather (half traffic), LDS-free MFMA bf16 GEMM (fp32 accum).

#define HDIM 128
#define SCAN_CHUNK 2048   // elements per block in the scan (256 thr x 8)

typedef __bf16 bf16x8 __attribute__((ext_vector_type(8)));
typedef float floatx4 __attribute__((ext_vector_type(4)));

__device__ __forceinline__ unsigned short f2bf(float f) {
    unsigned int u = __float_as_uint(f);
    unsigned int r = (u + 0x7fff + ((u >> 16) & 1)) >> 16;   // RNE
    return (unsigned short)r;
}
__device__ __forceinline__ float bf2f(unsigned short b) {
    return __uint_as_float((unsigned int)b << 16);
}

__global__ void k_detect(const int* __restrict__ edge, int nwords, int* __restrict__ flag) {
    // If edge is int64 (little-endian, values < 2^31), every odd 32-bit word is 0.
    __shared__ int s_or;
    if (threadIdx.x == 0) s_or = 0;
    __syncthreads();
    int i = threadIdx.x * 2 + 1;
    int v = (i < nwords) ? edge[i] : 0;
    if (v != 0) atomicOr(&s_or, 1);
    __syncthreads();
    if (threadIdx.x == 0) flag[0] = (s_or == 0) ? 1 : 0;  // shift: 1 => int64, 0 => int32
}

__global__ void k_zero(int* __restrict__ p, int n) {
    int i = blockIdx.x * blockDim.x + threadIdx.x;
    if (i < n) p[i] = 0;
}

__global__ void k_count(const int* __restrict__ edge, int E, const int* __restrict__ flag,
                        int* __restrict__ deg) {
    int sh = flag[0];
    int i = blockIdx.x * blockDim.x + threadIdx.x;
    if (i < E) {
        int d = edge[(size_t)(E + i) << sh];
        atomicAdd(&deg[d], 1);
    }
}

// ---- 3-phase scan: deg[N] -> off[N+1] (exclusive) ----
__global__ __launch_bounds__(256) void k_scan1(const int* __restrict__ deg, int N,
                                               int* __restrict__ partial) {
    __shared__ int sm[256];
    int t = threadIdx.x;
    int base = blockIdx.x * SCAN_CHUNK + t * 8;
    int s = 0;
#pragma unroll
    for (int j = 0; j < 8; ++j) {
        int i = base + j;
        if (i < N) s += deg[i];
    }
    sm[t] = s;
    __syncthreads();
    for (int st = 128; st > 0; st >>= 1) {
        if (t < st) sm[t] += sm[t + st];
        __syncthreads();
    }
    if (t == 0) partial[blockIdx.x] = sm[0];
}

__global__ __launch_bounds__(256) void k_scan2(int* __restrict__ partial, int nb) {
    __shared__ int sm[256];
    int t = threadIdx.x;
    int v = (t < nb) ? partial[t] : 0;
    sm[t] = v;
    __syncthreads();
    for (int st = 1; st < 256; st <<= 1) {
        int tv = (t >= st) ? sm[t - st] : 0;
        __syncthreads();
        sm[t] += tv;
        __syncthreads();
    }
    if (t < nb) partial[t] = sm[t] - v;  // exclusive
}

__global__ __launch_bounds__(256) void k_scan3(const int* __restrict__ deg, int N,
                                               const int* __restrict__ partial,
                                               int* __restrict__ off) {
    __shared__ int sm[256];
    int t = threadIdx.x;
    int b = blockIdx.x;
    int base = b * SCAN_CHUNK + t * 8;
    int v[8];
    int s = 0;
#pragma unroll
    for (int j = 0; j < 8; ++j) {
        int i = base + j;
        v[j] = (i < N) ? deg[i] : 0;
        s += v[j];
    }
    sm[t] = s;
    __syncthreads();
    for (int st = 1; st < 256; st <<= 1) {
        int tv = (t >= st) ? sm[t - st] : 0;
        __syncthreads();
        sm[t] += tv;
        __syncthreads();
    }
    int run = partial[b] + sm[t] - s;
#pragma unroll
    for (int j = 0; j < 8; ++j) {
        int i = base + j;
        if (i < N) {
            off[i] = run;
            run += v[j];
        }
    }
    if (b == gridDim.x - 1 && t == 255) off[N] = partial[b] + sm[255];
}

// Bucket edges into CSR slots, writing packed {src, att} pairs directly.
__global__ void k_fill(const int* __restrict__ edge, int E, const int* __restrict__ flag,
                       const float* __restrict__ att,
                       const int* __restrict__ off, int* __restrict__ cursor,
                       float2* __restrict__ pse) {
    int sh = flag[0];
    int i = blockIdx.x * blockDim.x + threadIdx.x;
    if (i < E) {
        int s = edge[(size_t)i << sh];        // src
        int d = edge[(size_t)(E + i) << sh];  // dst
        int pos = off[d] + atomicAdd(&cursor[d], 1);
        pse[pos] = make_float2(__int_as_float(s), att[i]);
    }
}

// fp32 -> bf16 cast, 4 elems/thread
__global__ void k_cast(const float* __restrict__ in, unsigned short* __restrict__ out, int n4) {
    int i = blockIdx.x * blockDim.x + threadIdx.x;
    if (i < n4) {
        float4 v = ((const float4*)in)[i];
        ushort4 o;
        o.x = f2bf(v.x); o.y = f2bf(v.y); o.z = f2bf(v.z); o.w = f2bf(v.w);
        ((ushort4*)out)[i] = o;
    }
}

// W[256,128] fp32 -> Wt[128,256] bf16 (transposed)
__global__ void k_prepW(const float* __restrict__ w, unsigned short* __restrict__ wt) {
    int t = blockIdx.x * blockDim.x + threadIdx.x;   // 0..32767
    if (t < 256 * 128) {
        int k = t >> 7;      // 0..255
        int n = t & 127;     // 0..127
        wt[(size_t)n * 256 + k] = f2bf(w[(size_t)k * 128 + n]);
    }
}

// One block (128 threads = 2 waves) per node, bf16 in/out, fp32 accumulate.
// agg = mean_{e: dst=n}( x[src[e]] * att[e] );  cat[n] = [ x[n], agg ]
__global__ __launch_bounds__(128) void k_agg(const unsigned short* __restrict__ x,
                                             const float2* __restrict__ pse,
                                             const int* __restrict__ off,
                                             unsigned short* __restrict__ cat, int N) {
    int n = blockIdx.x;
    int h = threadIdx.x;  // 0..127
    __shared__ float2 sp[128];
    int o0 = off[n], o1 = off[n + 1];
    int deg = o1 - o0;
    float sum = 0.f;
    for (int base = 0; base < deg; base += 128) {
        int cnt = min(128, deg - base);
        __syncthreads();
        if (h < cnt) sp[h] = pse[o0 + base + h];
        __syncthreads();
        int j = 0;
        for (; j + 4 <= cnt; j += 4) {
            float2 p0 = sp[j + 0];
            float2 p1 = sp[j + 1];
            float2 p2 = sp[j + 2];
            float2 p3 = sp[j + 3];
            float v0 = bf2f(x[(size_t)__float_as_int(p0.x) * HDIM + h]);
            float v1 = bf2f(x[(size_t)__float_as_int(p1.x) * HDIM + h]);
            float v2 = bf2f(x[(size_t)__float_as_int(p2.x) * HDIM + h]);
            float v3 = bf2f(x[(size_t)__float_as_int(p3.x) * HDIM + h]);
            sum = fmaf(v0, p0.y, sum);
            sum = fmaf(v1, p1.y, sum);
            sum = fmaf(v2, p2.y, sum);
            sum = fmaf(v3, p3.y, sum);
        }
        for (; j < cnt; ++j) {
            float2 p = sp[j];
            sum = fmaf(bf2f(x[(size_t)__float_as_int(p.x) * HDIM + h]), p.y, sum);
        }
    }
    float m = fmaxf((float)deg, 1.0f);
    cat[(size_t)n * 256 + h] = x[(size_t)n * HDIM + h];       // raw bf16 copy
    cat[(size_t)n * 256 + 128 + h] = f2bf(sum / m);
}

// out[M,128] = relu( A[M,256]bf16 @ W[256,128] + b ), MFMA 16x16x32, fp32 accum.
// LDS-free: A-frags from global (A layout m=lane&15, k=quad*8+j),
// B-frags from pre-transposed Wt[128,256] bf16. C/D: col=lane&15, row=quad*4+reg.
// Block = 4 waves; wave w -> rows blk*64 + 16w .. +15, all 128 cols (8 tiles).
__global__ __launch_bounds__(256) void k_gemm_mfma(const unsigned short* __restrict__ A,
                                                   const unsigned short* __restrict__ Wt,
                                                   const float* __restrict__ bias,
                                                   float* __restrict__ outF,
                                                   unsigned short* __restrict__ outB,
                                                   int M) {
    int tid = threadIdx.x;
    int wave = tid >> 6;
    int lane = tid & 63;
    int l16 = lane & 15;
    int quad = lane >> 4;

    int row = blockIdx.x * 64 + wave * 16 + l16;
    int rowA = min(row, M - 1);
    const unsigned short* aptr = A + (size_t)rowA * 256 + quad * 8;

    floatx4 acc[8];
#pragma unroll
    for (int c = 0; c < 8; ++c) acc[c] = (floatx4){0.f, 0.f, 0.f, 0.f};

#pragma unroll
    for (int kc = 0; kc < 8; ++kc) {
        bf16x8 af = *(const bf16x8*)(aptr + kc * 32);
#pragma unroll
        for (int c = 0; c < 8; ++c) {
            const unsigned short* bptr = Wt + (size_t)(c * 16 + l16) * 256 + kc * 32 + quad * 8;
            bf16x8 bfr = *(const bf16x8*)bptr;
            acc[c] = __builtin_amdgcn_mfma_f32_16x16x32_bf16(af, bfr, acc[c], 0, 0, 0);
        }
    }

    int orow0 = blockIdx.x * 64 + wave * 16 + quad * 4;
#pragma unroll
    for (int c = 0; c < 8; ++c) {
        int col = c * 16 + l16;
        float bv = bias[col];
#pragma unroll
        for (int r = 0; r < 4; ++r) {
            int orow = orow0 + r;
            if (orow < M) {
                float v = fmaxf(acc[c][r] + bv, 0.f);
                if (outF) outF[(size_t)orow * 128 + col] = v;
                else outB[(size_t)orow * 128 + col] = f2bf(v);
            }
        }
    }
}

extern "C" void kernel_launch(void* const* d_in, const int* in_sizes, int n_in,
                              void* d_out, int out_size, void* d_ws, size_t ws_size,
                              hipStream_t stream) {
    const float* data = (const float*)d_in[0];
    const int* edge = (const int*)d_in[1];
    const float* att = (const float*)d_in[2];
    const float* w1 = (const float*)d_in[3];
    const float* b1 = (const float*)d_in[4];
    const float* w2 = (const float*)d_in[5];
    const float* b2 = (const float*)d_in[6];

    const int N = in_sizes[0] / HDIM;
    const int E = in_sizes[1] / 2;

    char* ws = (char*)d_ws;
    size_t o = 0;
    auto carve = [&](size_t bytes) -> char* {
        char* r = ws + o;
        o = (o + bytes + 255) & ~(size_t)255;
        return r;
    };
    int* flag = (int*)carve(16);
    int* deg = (int*)carve((size_t)2 * N * 4);  // deg[N] + cursor[N]
    int* cursor = deg + N;
    int* off = (int*)carve((size_t)(N + 1) * 4);
    int* partial = (int*)carve(256 * 4);
    float2* pse = (float2*)carve((size_t)E * 8);             // packed {src, att} CSR
    unsigned short* data_bf = (unsigned short*)carve((size_t)N * 128 * 2);
    unsigned short* w1t = (unsigned short*)carve(256 * 128 * 2);
    unsigned short* w2t = (unsigned short*)carve(256 * 128 * 2);
    unsigned short* cat_bf = (unsigned short*)carve((size_t)N * 256 * 2);
    unsigned short* out1_bf = (unsigned short*)carve((size_t)N * 128 * 2);
    float* outF = (float*)d_out;

    int nw = 2 * E < 512 ? 2 * E : 512;
    k_detect<<<1, 256, 0, stream>>>(edge, nw, flag);
    k_zero<<<(2 * N + 255) / 256, 256, 0, stream>>>(deg, 2 * N);
    k_count<<<(E + 255) / 256, 256, 0, stream>>>(edge, E, flag, deg);

    int nb = (N + SCAN_CHUNK - 1) / SCAN_CHUNK;  // 25 for N=50000
    k_scan1<<<nb, 256, 0, stream>>>(deg, N, partial);
    k_scan2<<<1, 256, 0, stream>>>(partial, nb);
    k_scan3<<<nb, 256, 0, stream>>>(deg, N, partial, off);

    k_fill<<<(E + 255) / 256, 256, 0, stream>>>(edge, E, flag, att, off, cursor, pse);

    int n4 = N * 128 / 4;
    k_cast<<<(n4 + 255) / 256, 256, 0, stream>>>(data, data_bf, n4);
    k_prepW<<<128, 256, 0, stream>>>(w1, w1t);
    k_prepW<<<128, 256, 0, stream>>>(w2, w2t);

    int gb = (N + 63) / 64;
    // Layer 1
    k_agg<<<N, 128, 0, stream>>>(data_bf, pse, off, cat_bf, N);
    k_gemm_mfma<<<gb, 256, 0, stream>>>(cat_bf, w1t, b1, nullptr, out1_bf, N);
    // Layer 2
    k_agg<<<N, 128, 0, stream>>>(out1_bf, pse, off, cat_bf, N);
    k_gemm_mfma<<<gb, 256, 0, stream>>>(cat_bf, w2t, b2, outF, nullptr, N);
}

// Round 5
// 304.511 us; speedup vs baseline: 1.9538x; 1.0841x over previous
//
#include <hip/hip_runtime.h>

// GNN: 2 x (SimpleConv(mean, cat) -> Linear(256->128) -> ReLU)
// N=50000 nodes, E=640000 edges, H=128.
//
// R1: k_agg latency-bound -> packed (src,att) CSR + LDS stage + x4 unroll.
// R2: k_scan single-block 90us -> 3-phase multi-block scan.
// R3: bf16 hidden pipeline + LDS-free MFMA bf16 GEMM (fp32 accum).
// R4: k_agg one-wave-per-node ushort2 gathers (half the gather instrs),
//     drop the x-copy half of cat: GEMM reads A = [X | AGG] from two buffers.

#define HDIM 128
#define SCAN_CHUNK 2048   // elements per block in the scan (256 thr x 8)

typedef __bf16 bf16x8 __attribute__((ext_vector_type(8)));
typedef float floatx4 __attribute__((ext_vector_type(4)));

__device__ __forceinline__ unsigned short f2bf(float f) {
    unsigned int u = __float_as_uint(f);
    unsigned int r = (u + 0x7fff + ((u >> 16) & 1)) >> 16;   // RNE
    return (unsigned short)r;
}
__device__ __forceinline__ float bf2f(unsigned short b) {
    return __uint_as_float((unsigned int)b << 16);
}

__global__ void k_detect(const int* __restrict__ edge, int nwords, int* __restrict__ flag) {
    // If edge is int64 (little-endian, values < 2^31), every odd 32-bit word is 0.
    __shared__ int s_or;
    if (threadIdx.x == 0) s_or = 0;
    __syncthreads();
    int i = threadIdx.x * 2 + 1;
    int v = (i < nwords) ? edge[i] : 0;
    if (v != 0) atomicOr(&s_or, 1);
    __syncthreads();
    if (threadIdx.x == 0) flag[0] = (s_or == 0) ? 1 : 0;  // shift: 1 => int64, 0 => int32
}

__global__ void k_zero(int* __restrict__ p, int n) {
    int i = blockIdx.x * blockDim.x + threadIdx.x;
    if (i < n) p[i] = 0;
}

__global__ void k_count(const int* __restrict__ edge, int E, const int* __restrict__ flag,
                        int* __restrict__ deg) {
    int sh = flag[0];
    int i = blockIdx.x * blockDim.x + threadIdx.x;
    if (i < E) {
        int d = edge[(size_t)(E + i) << sh];
        atomicAdd(&deg[d], 1);
    }
}

// ---- 3-phase scan: deg[N] -> off[N+1] (exclusive) ----
__global__ __launch_bounds__(256) void k_scan1(const int* __restrict__ deg, int N,
                                               int* __restrict__ partial) {
    __shared__ int sm[256];
    int t = threadIdx.x;
    int base = blockIdx.x * SCAN_CHUNK + t * 8;
    int s = 0;
#pragma unroll
    for (int j = 0; j < 8; ++j) {
        int i = base + j;
        if (i < N) s += deg[i];
    }
    sm[t] = s;
    __syncthreads();
    for (int st = 128; st > 0; st >>= 1) {
        if (t < st) sm[t] += sm[t + st];
        __syncthreads();
    }
    if (t == 0) partial[blockIdx.x] = sm[0];
}

__global__ __launch_bounds__(256) void k_scan2(int* __restrict__ partial, int nb) {
    __shared__ int sm[256];
    int t = threadIdx.x;
    int v = (t < nb) ? partial[t] : 0;
    sm[t] = v;
    __syncthreads();
    for (int st = 1; st < 256; st <<= 1) {
        int tv = (t >= st) ? sm[t - st] : 0;
        __syncthreads();
        sm[t] += tv;
        __syncthreads();
    }
    if (t < nb) partial[t] = sm[t] - v;  // exclusive
}

__global__ __launch_bounds__(256) void k_scan3(const int* __restrict__ deg, int N,
                                               const int* __restrict__ partial,
                                               int* __restrict__ off) {
    __shared__ int sm[256];
    int t = threadIdx.x;
    int b = blockIdx.x;
    int base = b * SCAN_CHUNK + t * 8;
    int v[8];
    int s = 0;
#pragma unroll
    for (int j = 0; j < 8; ++j) {
        int i = base + j;
        v[j] = (i < N) ? deg[i] : 0;
        s += v[j];
    }
    sm[t] = s;
    __syncthreads();
    for (int st = 1; st < 256; st <<= 1) {
        int tv = (t >= st) ? sm[t - st] : 0;
        __syncthreads();
        sm[t] += tv;
        __syncthreads();
    }
    int run = partial[b] + sm[t] - s;
#pragma unroll
    for (int j = 0; j < 8; ++j) {
        int i = base + j;
        if (i < N) {
            off[i] = run;
            run += v[j];
        }
    }
    if (b == gridDim.x - 1 && t == 255) off[N] = partial[b] + sm[255];
}

// Bucket edges into CSR slots, writing packed {src, att} pairs directly.
__global__ void k_fill(const int* __restrict__ edge, int E, const int* __restrict__ flag,
                       const float* __restrict__ att,
                       const int* __restrict__ off, int* __restrict__ cursor,
                       float2* __restrict__ pse) {
    int sh = flag[0];
    int i = blockIdx.x * blockDim.x + threadIdx.x;
    if (i < E) {
        int s = edge[(size_t)i << sh];        // src
        int d = edge[(size_t)(E + i) << sh];  // dst
        int pos = off[d] + atomicAdd(&cursor[d], 1);
        pse[pos] = make_float2(__int_as_float(s), att[i]);
    }
}

// fp32 -> bf16 cast, 4 elems/thread
__global__ void k_cast(const float* __restrict__ in, unsigned short* __restrict__ out, int n4) {
    int i = blockIdx.x * blockDim.x + threadIdx.x;
    if (i < n4) {
        float4 v = ((const float4*)in)[i];
        ushort4 o;
        o.x = f2bf(v.x); o.y = f2bf(v.y); o.z = f2bf(v.z); o.w = f2bf(v.w);
        ((ushort4*)out)[i] = o;
    }
}

// W[256,128] fp32 -> Wt[128,256] bf16 (transposed)
__global__ void k_prepW(const float* __restrict__ w, unsigned short* __restrict__ wt) {
    int t = blockIdx.x * blockDim.x + threadIdx.x;   // 0..32767
    if (t < 256 * 128) {
        int k = t >> 7;      // 0..255
        int n = t & 127;     // 0..127
        wt[(size_t)n * 256 + k] = f2bf(w[(size_t)k * 128 + n]);
    }
}

// One WAVE per node, 2 nodes per 128-thread block. Each lane covers 2 columns
// via ushort2 (4B) gathers. agg[n] = mean_{e: dst=n}( x[src[e]] * att[e] ).
// Block-uniform outer trip count (max deg of the 2 nodes) keeps barriers legal.
__global__ __launch_bounds__(128) void k_agg(const unsigned short* __restrict__ x,
                                             const float2* __restrict__ pse,
                                             const int* __restrict__ off,
                                             unsigned short* __restrict__ agg, int N) {
    int wave = threadIdx.x >> 6;
    int lane = threadIdx.x & 63;
    int n = blockIdx.x * 2 + wave;
    bool valid = n < N;
    int o0 = 0, o1 = 0;
    if (valid) { o0 = off[n]; o1 = off[n + 1]; }
    int deg = o1 - o0;

    __shared__ int sdeg[2];
    __shared__ float2 sp[2][64];
    if (lane == 0) sdeg[wave] = deg;
    __syncthreads();
    int maxdeg = max(sdeg[0], sdeg[1]);

    float sx = 0.f, sy = 0.f;
    for (int base = 0; base < maxdeg; base += 64) {
        int cnt = min(64, deg - base);  // per-wave; may be <= 0
        __syncthreads();
        if (base + lane < deg) sp[wave][lane] = pse[o0 + base + lane];
        __syncthreads();
        int j = 0;
        for (; j + 4 <= cnt; j += 4) {
            float2 p0 = sp[wave][j + 0];
            float2 p1 = sp[wave][j + 1];
            float2 p2 = sp[wave][j + 2];
            float2 p3 = sp[wave][j + 3];
            unsigned int u0 = *(const unsigned int*)(x + (size_t)__float_as_int(p0.x) * HDIM + 2 * lane);
            unsigned int u1 = *(const unsigned int*)(x + (size_t)__float_as_int(p1.x) * HDIM + 2 * lane);
            unsigned int u2 = *(const unsigned int*)(x + (size_t)__float_as_int(p2.x) * HDIM + 2 * lane);
            unsigned int u3 = *(const unsigned int*)(x + (size_t)__float_as_int(p3.x) * HDIM + 2 * lane);
            sx = fmaf(bf2f((unsigned short)(u0 & 0xffff)), p0.y, sx);
            sy = fmaf(bf2f((unsigned short)(u0 >> 16)), p0.y, sy);
            sx = fmaf(bf2f((unsigned short)(u1 & 0xffff)), p1.y, sx);
            sy = fmaf(bf2f((unsigned short)(u1 >> 16)), p1.y, sy);
            sx = fmaf(bf2f((unsigned short)(u2 & 0xffff)), p2.y, sx);
            sy = fmaf(bf2f((unsigned short)(u2 >> 16)), p2.y, sy);
            sx = fmaf(bf2f((unsigned short)(u3 & 0xffff)), p3.y, sx);
            sy = fmaf(bf2f((unsigned short)(u3 >> 16)), p3.y, sy);
        }
        for (; j < cnt; ++j) {
            float2 p = sp[wave][j];
            unsigned int u = *(const unsigned int*)(x + (size_t)__float_as_int(p.x) * HDIM + 2 * lane);
            sx = fmaf(bf2f((unsigned short)(u & 0xffff)), p.y, sx);
            sy = fmaf(bf2f((unsigned short)(u >> 16)), p.y, sy);
        }
    }
    if (valid) {
        float m = fmaxf((float)deg, 1.0f);
        unsigned int o = (unsigned int)f2bf(sx / m) | ((unsigned int)f2bf(sy / m) << 16);
        *(unsigned int*)(agg + (size_t)n * HDIM + 2 * lane) = o;
    }
}

// out[M,128] = relu( [X | AGG][M,256]bf16 @ W[256,128] + b ), MFMA 16x16x32.
// LDS-free: A-frags from X (k<128) / AGG (k>=128); B-frags from Wt[128,256].
// C/D: col=lane&15, row=quad*4+reg. Block = 4 waves, 64 rows/block.
__global__ __launch_bounds__(256) void k_gemm_mfma(const unsigned short* __restrict__ X,
                                                   const unsigned short* __restrict__ AGG,
                                                   const unsigned short* __restrict__ Wt,
                                                   const float* __restrict__ bias,
                                                   float* __restrict__ outF,
                                                   unsigned short* __restrict__ outB,
                                                   int M) {
    int tid = threadIdx.x;
    int wave = tid >> 6;
    int lane = tid & 63;
    int l16 = lane & 15;
    int quad = lane >> 4;

    int row = blockIdx.x * 64 + wave * 16 + l16;
    int rowA = min(row, M - 1);
    const unsigned short* xrow = X + (size_t)rowA * HDIM + quad * 8;
    const unsigned short* arow = AGG + (size_t)rowA * HDIM + quad * 8;

    floatx4 acc[8];
#pragma unroll
    for (int c = 0; c < 8; ++c) acc[c] = (floatx4){0.f, 0.f, 0.f, 0.f};

#pragma unroll
    for (int kc = 0; kc < 8; ++kc) {
        bf16x8 af = (kc < 4) ? *(const bf16x8*)(xrow + kc * 32)
                             : *(const bf16x8*)(arow + (kc - 4) * 32);
#pragma unroll
        for (int c = 0; c < 8; ++c) {
            const unsigned short* bptr = Wt + (size_t)(c * 16 + l16) * 256 + kc * 32 + quad * 8;
            bf16x8 bfr = *(const bf16x8*)bptr;
            acc[c] = __builtin_amdgcn_mfma_f32_16x16x32_bf16(af, bfr, acc[c], 0, 0, 0);
        }
    }

    int orow0 = blockIdx.x * 64 + wave * 16 + quad * 4;
#pragma unroll
    for (int c = 0; c < 8; ++c) {
        int col = c * 16 + l16;
        float bv = bias[col];
#pragma unroll
        for (int r = 0; r < 4; ++r) {
            int orow = orow0 + r;
            if (orow < M) {
                float v = fmaxf(acc[c][r] + bv, 0.f);
                if (outF) outF[(size_t)orow * 128 + col] = v;
                else outB[(size_t)orow * 128 + col] = f2bf(v);
            }
        }
    }
}

extern "C" void kernel_launch(void* const* d_in, const int* in_sizes, int n_in,
                              void* d_out, int out_size, void* d_ws, size_t ws_size,
                              hipStream_t stream) {
    const float* data = (const float*)d_in[0];
    const int* edge = (const int*)d_in[1];
    const float* att = (const float*)d_in[2];
    const float* w1 = (const float*)d_in[3];
    const float* b1 = (const float*)d_in[4];
    const float* w2 = (const float*)d_in[5];
    const float* b2 = (const float*)d_in[6];

    const int N = in_sizes[0] / HDIM;
    const int E = in_sizes[1] / 2;

    char* ws = (char*)d_ws;
    size_t o = 0;
    auto carve = [&](size_t bytes) -> char* {
        char* r = ws + o;
        o = (o + bytes + 255) & ~(size_t)255;
        return r;
    };
    int* flag = (int*)carve(16);
    int* deg = (int*)carve((size_t)2 * N * 4);  // deg[N] + cursor[N]
    int* cursor = deg + N;
    int* off = (int*)carve((size_t)(N + 1) * 4);
    int* partial = (int*)carve(256 * 4);
    float2* pse = (float2*)carve((size_t)E * 8);             // packed {src, att} CSR
    unsigned short* data_bf = (unsigned short*)carve((size_t)N * 128 * 2);
    unsigned short* w1t = (unsigned short*)carve(256 * 128 * 2);
    unsigned short* w2t = (unsigned short*)carve(256 * 128 * 2);
    unsigned short* agg_bf = (unsigned short*)carve((size_t)N * 128 * 2);
    unsigned short* out1_bf = (unsigned short*)carve((size_t)N * 128 * 2);
    float* outF = (float*)d_out;

    int nw = 2 * E < 512 ? 2 * E : 512;
    k_detect<<<1, 256, 0, stream>>>(edge, nw, flag);
    k_zero<<<(2 * N + 255) / 256, 256, 0, stream>>>(deg, 2 * N);
    k_count<<<(E + 255) / 256, 256, 0, stream>>>(edge, E, flag, deg);

    int nb = (N + SCAN_CHUNK - 1) / SCAN_CHUNK;  // 25 for N=50000
    k_scan1<<<nb, 256, 0, stream>>>(deg, N, partial);
    k_scan2<<<1, 256, 0, stream>>>(partial, nb);
    k_scan3<<<nb, 256, 0, stream>>>(deg, N, partial, off);

    k_fill<<<(E + 255) / 256, 256, 0, stream>>>(edge, E, flag, att, off, cursor, pse);

    int n4 = N * 128 / 4;
    k_cast<<<(n4 + 255) / 256, 256, 0, stream>>>(data, data_bf, n4);
    k_prepW<<<128, 256, 0, stream>>>(w1, w1t);
    k_prepW<<<128, 256, 0, stream>>>(w2, w2t);

    int ga = (N + 1) / 2;
    int gb = (N + 63) / 64;
    // Layer 1
    k_agg<<<ga, 128, 0, stream>>>(data_bf, pse, off, agg_bf, N);
    k_gemm_mfma<<<gb, 256, 0, stream>>>(data_bf, agg_bf, w1t, b1, nullptr, out1_bf, N);
    // Layer 2
    k_agg<<<ga, 128, 0, stream>>>(out1_bf, pse, off, agg_bf, N);
    k_gemm_mfma<<<gb, 256, 0, stream>>>(out1_bf, agg_bf, w2t, b2, outF, nullptr, N);
}